// Round 9
// baseline (533.320 us; speedup 1.0000x reference)
//
#include <hip/hip_runtime.h>
#include <stdint.h>

#define H_N 16
#define S_N 2048
#define D_N 64
#define QB  64
#define KT  64

typedef __attribute__((ext_vector_type(8))) __bf16 bf16x8;
typedef __attribute__((ext_vector_type(4))) float f32x4;

__device__ __forceinline__ unsigned short f2bf(float f) {
  uint32_t u = __float_as_uint(f);
  u += 0x7FFFu + ((u >> 16) & 1u);   // round-to-nearest-even
  return (unsigned short)(u >> 16);
}

// JAX threefry2x32, key=(0,42): full 20-round block, both output lanes.
__device__ __forceinline__ uint2 tf2x32(uint32_t c0, uint32_t c1) {
  const uint32_t K0 = 0u, K1 = 42u, K2 = 0x1BD11BDAu ^ 42u;
  uint32_t x0 = c0 + K0, x1 = c1 + K1;
#define TFR(r) x0 += x1; x1 = __builtin_rotateleft32(x1, r); x1 ^= x0;
  TFR(13) TFR(15) TFR(26) TFR(6)
  x0 += K1; x1 += K2 + 1u;
  TFR(17) TFR(29) TFR(16) TFR(24)
  x0 += K2; x1 += K0 + 2u;
  TFR(13) TFR(15) TFR(26) TFR(6)
  x0 += K0; x1 += K1 + 3u;
  TFR(17) TFR(29) TFR(16) TFR(24)
  x0 += K1; x1 += K2 + 4u;
  TFR(13) TFR(15) TFR(26) TFR(6)
  x0 += K2; x1 += K0 + 5u;
#undef TFR
  return make_uint2(x0, x1);
}

// Modern JAX partitionable random_bits(32) at flat index j:
// bits = x0 ^ x1 of threefry(key,(0,j)); keep <=> bits < 0x733333<<9.
__device__ __forceinline__ bool keep_bit(uint32_t j) {
  uint2 o = tf2x32(0u, j);
  return ((o.x ^ o.y) < 0xE6666600u);
}

// --- async-STAGE split for 512 threads: each thread owns 8 floats ---
struct StageReg8 { float4 a, b; };

__device__ __forceinline__ void stageLoad8(const float* __restrict__ g, int tid,
                                           StageReg8& r) {
  const float4* s = (const float4*)(g + (tid << 3));
  r.a = s[0]; r.b = s[1];
}

// [64 rows][64 cols] f32 (regs) -> bf16 LDS, XOR-swizzled.
// ushort idx for (row,col): row*64 + (((col>>3)^(row&7))<<3) + (col&7)
__device__ __forceinline__ void stageWrite8(const StageReg8& r,
                                            unsigned short* __restrict__ lds, int tid) {
  const int row = tid >> 3;
  const int c   = tid & 7;          // 8-elt chunk index
  uint4 q;
  q.x = (uint32_t)f2bf(r.a.x) | ((uint32_t)f2bf(r.a.y) << 16);
  q.y = (uint32_t)f2bf(r.a.z) | ((uint32_t)f2bf(r.a.w) << 16);
  q.z = (uint32_t)f2bf(r.b.x) | ((uint32_t)f2bf(r.b.y) << 16);
  q.w = (uint32_t)f2bf(r.b.z) | ((uint32_t)f2bf(r.b.w) << 16);
  *(uint4*)&lds[row * 64 + ((c ^ (row & 7)) << 3)] = q;
}

// V tile (regs) -> TRANSPOSED bf16 LDS [d][key], swizzled.
__device__ __forceinline__ void stageWriteT8(const StageReg8& r,
                                             unsigned short* __restrict__ lds, int tid) {
  const int key = tid >> 3;
  const int d0  = (tid & 7) * 8;
  const int kc = key >> 3, ke = key & 7;
#define WRT(e, val) { const int dd = d0 + (e); \
    lds[dd * 64 + (((kc ^ (dd & 7)) << 3) | ke)] = f2bf(val); }
  WRT(0, r.a.x) WRT(1, r.a.y) WRT(2, r.a.z) WRT(3, r.a.w)
  WRT(4, r.b.x) WRT(5, r.b.y) WRT(6, r.b.z) WRT(7, r.b.w)
#undef WRT
}

__global__ __launch_bounds__(512, 8)
void attn_fused(const float* __restrict__ Q, const float* __restrict__ K,
                const float* __restrict__ V, const int* __restrict__ mask,
                float* __restrict__ outO, float* __restrict__ outP) {
  __shared__ uint4 smemRaw[1536];               // 24 KB
  __shared__ float part[2][64];                 // cross-k-half row sums
  unsigned short* const sbase = (unsigned short*)smemRaw;
  unsigned short* const sQP = sbase;            // Q tile, then aliased as P tile
  unsigned short* const sK  = sbase + 4096;
  unsigned short* const sV  = sbase + 8192;

  const int tid = threadIdx.x;
  const int l   = tid & 63;
  const int w   = tid >> 6;                     // 8 warps
  const int wq  = w & 3;                        // q-quarter (16 rows)
  const int wk  = w >> 2;                       // k-half (32 cols)
  const int bid = blockIdx.x;
  const int b   = bid & 1;
  const int h   = (bid >> 1) & (H_N - 1);
  const int qt  = bid >> 5;
  const int qBase = qt * QB;

  const int lrow = l & 15;
  const int lq4  = l >> 4;

  const size_t base = ((size_t)b * H_N + h) * (size_t)(S_N * D_N);
  const int* const maskRow = mask + b * S_N;

  // ---- stage Q, load A-frags (per-warp q-quarter)
  {
    StageReg8 qreg;
    stageLoad8(Q + base + (size_t)qBase * D_N, tid, qreg);
    stageWrite8(qreg, sQP, tid);
  }
  __syncthreads();

  bf16x8 qf[2];
  {
    const int qrow = wq * 16 + lrow;
#pragma unroll
    for (int ks = 0; ks < 2; ++ks) {
      const int cc = ks * 4 + lq4;
      qf[ks] = *(const bf16x8*)&sQP[qrow * 64 + ((cc ^ (qrow & 7)) << 3)];
    }
  }

  // ---- pass 1: row sums of mask * exp(score - 20); each warp its k-half
  float minv[4];
  {
    float lsum[4] = {0.f, 0.f, 0.f, 0.f};
    StageReg8 kreg;
    stageLoad8(K + base, tid, kreg);
    for (int kt = 0; kt < S_N / KT; ++kt) {
      __syncthreads();
      stageWrite8(kreg, sK, tid);
      __syncthreads();
      if (kt + 1 < S_N / KT)
        stageLoad8(K + base + (size_t)((kt + 1) * KT) * D_N, tid, kreg);
#pragma unroll
      for (int n = 0; n < 2; ++n) {
        const int krow = wk * 32 + n * 16 + lrow;
        f32x4 acc = {0.f, 0.f, 0.f, 0.f};
#pragma unroll
        for (int ks = 0; ks < 2; ++ks) {
          const int cc = ks * 4 + lq4;
          bf16x8 kf = *(const bf16x8*)&sK[krow * 64 + ((cc ^ (krow & 7)) << 3)];
          acc = __builtin_amdgcn_mfma_f32_16x16x32_bf16(qf[ks], kf, acc, 0, 0, 0);
        }
        const float mf = (float)maskRow[kt * KT + krow];
#pragma unroll
        for (int r = 0; r < 4; ++r)
          lsum[r] += mf * __expf(acc[r] * 0.125f - 20.0f);
      }
    }
#pragma unroll
    for (int r = 0; r < 4; ++r) {
      float v = lsum[r];
      v += __shfl_xor(v, 1);
      v += __shfl_xor(v, 2);
      v += __shfl_xor(v, 4);
      v += __shfl_xor(v, 8);
      if (lrow == 0) part[wk][wq * 16 + lq4 * 4 + r] = v;
    }
    __syncthreads();
#pragma unroll
    for (int r = 0; r < 4; ++r) {
      const int row = wq * 16 + lq4 * 4 + r;
      const float v = part[0][row] + part[1][row];
      minv[r] = (v > 0.f) ? ((1.0f / 0.9f) / v) : 0.f;
    }
  }

  // ---- pass 2: scores, dropout, p-store, PV
  f32x4 oacc[2];
  oacc[0] = (f32x4){0.f, 0.f, 0.f, 0.f};
  oacc[1] = (f32x4){0.f, 0.f, 0.f, 0.f};

  const uint32_t qg = (uint32_t)(qBase + wq * 16 + lq4 * 4);
  const size_t pBase = ((size_t)b * H_N + h) * (size_t)(S_N * S_N);
  const uint32_t jBase = (uint32_t)(b * H_N + h) * 4194304u + qg * 2048u;

  {
    StageReg8 kreg, vreg;
    stageLoad8(K + base, tid, kreg);
    stageLoad8(V + base, tid, vreg);
    for (int kt = 0; kt < S_N / KT; ++kt) {
      __syncthreads();                          // prev tile's compute/PV done
      stageWrite8 (kreg, sK, tid);
      stageWriteT8(vreg, sV, tid);
      __syncthreads();
      if (kt + 1 < S_N / KT) {
        stageLoad8(K + base + (size_t)((kt + 1) * KT) * D_N, tid, kreg);
        stageLoad8(V + base + (size_t)((kt + 1) * KT) * D_N, tid, vreg);
      }

#pragma unroll
      for (int n = 0; n < 2; ++n) {
        const int krow = wk * 32 + n * 16 + lrow;
        f32x4 acc = {0.f, 0.f, 0.f, 0.f};
#pragma unroll
        for (int ks = 0; ks < 2; ++ks) {
          const int cc = ks * 4 + lq4;
          bf16x8 kf = *(const bf16x8*)&sK[krow * 64 + ((cc ^ (krow & 7)) << 3)];
          acc = __builtin_amdgcn_mfma_f32_16x16x32_bf16(qf[ks], kf, acc, 0, 0, 0);
        }
        const int kg = kt * KT + krow;
        const float mf = (float)maskRow[kg];
        const uint32_t j0 = jBase + (uint32_t)kg;
#pragma unroll
        for (int r = 0; r < 4; ++r) {
          const float pe = mf * __expf(acc[r] * 0.125f - 20.0f) * minv[r];
          const float pd = keep_bit(j0 + (uint32_t)r * 2048u) ? pe : 0.0f;
          __builtin_nontemporal_store(pd, &outP[pBase + (size_t)(qg + r) * S_N + (size_t)kg]);
          const int prow = wq * 16 + lq4 * 4 + r;
          sQP[prow * 64 + ((((krow >> 3) ^ (prow & 7)) << 3) | (krow & 7))] = f2bf(pd);
        }
      }
      __syncthreads();                          // P tile visible across warps
      // PV: out[q][d] += P[q][k] * V[k][d]; warp computes its (q-quarter, d-half)
#pragma unroll
      for (int ks = 0; ks < 2; ++ks) {
        const int cc = ks * 4 + lq4;
        const int prow = wq * 16 + lrow;
        bf16x8 af = *(const bf16x8*)&sQP[prow * 64 + ((cc ^ (prow & 7)) << 3)];
#pragma unroll
        for (int n = 0; n < 2; ++n) {
          const int vrow = wk * 32 + n * 16 + lrow;
          bf16x8 vf = *(const bf16x8*)&sV[vrow * 64 + ((cc ^ (vrow & 7)) << 3)];
          oacc[n] = __builtin_amdgcn_mfma_f32_16x16x32_bf16(af, vf, oacc[n], 0, 0, 0);
        }
      }
    }
  }

  // ---- store out: rows qg+r, cols wk*32 + n*16 + lrow
#pragma unroll
  for (int n = 0; n < 2; ++n)
#pragma unroll
    for (int r = 0; r < 4; ++r) {
      const size_t off = (((size_t)b * H_N + h) * S_N + (size_t)(qg + r)) * D_N
                       + wk * 32 + n * 16 + lrow;
      __builtin_nontemporal_store(oacc[n][r], &outO[off]);
    }
}

extern "C" void kernel_launch(void* const* d_in, const int* in_sizes, int n_in,
                              void* d_out, int out_size, void* d_ws, size_t ws_size,
                              hipStream_t stream) {
  const float* Q   = (const float*)d_in[0];
  const float* K   = (const float*)d_in[1];
  const float* V   = (const float*)d_in[2];
  const int* mask  = (const int*)d_in[3];
  float* outO = (float*)d_out;
  float* outP = outO + (size_t)2 * H_N * S_N * D_N;   // out first, then p_attn
  hipLaunchKernelGGL(attn_fused, dim3(1024), dim3(512), 0, stream,
                     Q, K, V, mask, outO, outP);
}

// Round 10
// 492.953 us; speedup vs baseline: 1.0819x; 1.0819x over previous
//
#include <hip/hip_runtime.h>
#include <stdint.h>

#define H_N 16
#define S_N 2048
#define D_N 64
#define QB  64
#define KT  64

typedef __attribute__((ext_vector_type(8))) __bf16 bf16x8;
typedef __attribute__((ext_vector_type(4))) float f32x4;

__device__ __forceinline__ unsigned short f2bf(float f) {
  uint32_t u = __float_as_uint(f);
  u += 0x7FFFu + ((u >> 16) & 1u);   // round-to-nearest-even
  return (unsigned short)(u >> 16);
}

// JAX threefry2x32, key=(0,42): full 20-round block, both output lanes.
__device__ __forceinline__ uint2 tf2x32(uint32_t c0, uint32_t c1) {
  const uint32_t K0 = 0u, K1 = 42u, K2 = 0x1BD11BDAu ^ 42u;
  uint32_t x0 = c0 + K0, x1 = c1 + K1;
#define TFR(r) x0 += x1; x1 = __builtin_rotateleft32(x1, r); x1 ^= x0;
  TFR(13) TFR(15) TFR(26) TFR(6)
  x0 += K1; x1 += K2 + 1u;
  TFR(17) TFR(29) TFR(16) TFR(24)
  x0 += K2; x1 += K0 + 2u;
  TFR(13) TFR(15) TFR(26) TFR(6)
  x0 += K0; x1 += K1 + 3u;
  TFR(17) TFR(29) TFR(16) TFR(24)
  x0 += K1; x1 += K2 + 4u;
  TFR(13) TFR(15) TFR(26) TFR(6)
  x0 += K2; x1 += K0 + 5u;
#undef TFR
  return make_uint2(x0, x1);
}

// bits = x0 ^ x1 of threefry(key,(0,j)); keep <=> bits < 0x733333<<9.
__device__ __forceinline__ bool keep_bit(uint32_t j) {
  uint2 o = tf2x32(0u, j);
  return ((o.x ^ o.y) < 0xE6666600u);
}

// ============ RNG kernel: keep-bit table, our layout ============
// word index w = (bh*2048 + k)*64 + qw  covers q in [qw*32, qw*32+32), fixed (bh,k).
// Wave lanes = qw 0..63 -> mask[b][k] is wave-uniform -> whole-wave skip on mask=0.
__global__ __launch_bounds__(256, 8)
void rng_bits(const int* __restrict__ mask, uint32_t* __restrict__ bits) {
  const uint32_t gid = blockIdx.x * 256u + threadIdx.x;   // < 4,194,304
  const uint32_t qw = gid & 63u;
  const uint32_t k  = (gid >> 6) & 2047u;
  const uint32_t bh = gid >> 17;
  const uint32_t b  = bh >> 4;
  if (mask[b * 2048u + k] == 0) { bits[gid] = 0u; return; }
  const uint32_t jb = bh * 4194304u + (qw << 5) * 2048u + k;
  uint32_t word = 0u;
#pragma unroll 8
  for (int i = 0; i < 32; ++i)
    word |= ((uint32_t)keep_bit(jb + (uint32_t)i * 2048u)) << i;
  bits[gid] = word;
}

// --- async-STAGE split helpers (256 threads: thread owns 16 floats) ---
struct StageReg { float4 a, b, c, d; };

__device__ __forceinline__ void stageLoad(const float* __restrict__ g, int tid,
                                          StageReg& r) {
  const float4* s = (const float4*)(g + (tid << 4));
  r.a = s[0]; r.b = s[1]; r.c = s[2]; r.d = s[3];
}

// [64 rows][64 cols] f32 (regs) -> bf16 LDS, XOR-swizzled.
// ushort idx for (row,col): row*64 + (((col>>3)^(row&7))<<3) + (col&7)
__device__ __forceinline__ void stageWrite(const StageReg& r,
                                           unsigned short* __restrict__ lds, int tid) {
  const int row = tid >> 2;
  const int c4  = tid & 3;
  uint4 q0, q1;
  q0.x = (uint32_t)f2bf(r.a.x) | ((uint32_t)f2bf(r.a.y) << 16);
  q0.y = (uint32_t)f2bf(r.a.z) | ((uint32_t)f2bf(r.a.w) << 16);
  q0.z = (uint32_t)f2bf(r.b.x) | ((uint32_t)f2bf(r.b.y) << 16);
  q0.w = (uint32_t)f2bf(r.b.z) | ((uint32_t)f2bf(r.b.w) << 16);
  q1.x = (uint32_t)f2bf(r.c.x) | ((uint32_t)f2bf(r.c.y) << 16);
  q1.y = (uint32_t)f2bf(r.c.z) | ((uint32_t)f2bf(r.c.w) << 16);
  q1.z = (uint32_t)f2bf(r.d.x) | ((uint32_t)f2bf(r.d.y) << 16);
  q1.w = (uint32_t)f2bf(r.d.z) | ((uint32_t)f2bf(r.d.w) << 16);
  const int rs = row & 7;
  *(uint4*)&lds[row * 64 + (((c4 * 2)     ^ rs) << 3)] = q0;
  *(uint4*)&lds[row * 64 + (((c4 * 2 + 1) ^ rs) << 3)] = q1;
}

// V tile (regs) -> TRANSPOSED bf16 LDS [d][key], swizzled.
__device__ __forceinline__ void stageWriteT(const StageReg& r,
                                            unsigned short* __restrict__ lds, int tid) {
  const int key = tid >> 2;
  const int c4  = tid & 3;
  const int kc = key >> 3, ke = key & 7;
#define WRT(e, val) { const int dd = c4 * 16 + (e); \
    lds[dd * 64 + (((kc ^ (dd & 7)) << 3) | ke)] = f2bf(val); }
  WRT(0,  r.a.x) WRT(1,  r.a.y) WRT(2,  r.a.z) WRT(3,  r.a.w)
  WRT(4,  r.b.x) WRT(5,  r.b.y) WRT(6,  r.b.z) WRT(7,  r.b.w)
  WRT(8,  r.c.x) WRT(9,  r.c.y) WRT(10, r.c.z) WRT(11, r.c.w)
  WRT(12, r.d.x) WRT(13, r.d.y) WRT(14, r.d.z) WRT(15, r.d.w)
#undef WRT
}

// exp(x*0.125 - 20) == exp2(x*0.18033688 - 28.853901)
#define EXPC1 0.18033688f
#define EXPC2 -28.853901f

// ============ Main fused attention; keep bits from table ============
__global__ __launch_bounds__(256, 4)
void attn_fused_bits(const float* __restrict__ Q, const float* __restrict__ K,
                     const float* __restrict__ V, const int* __restrict__ mask,
                     const uint32_t* __restrict__ bits,
                     float* __restrict__ outO, float* __restrict__ outP) {
  __shared__ uint4 smemRaw[2048];               // 32 KB
  unsigned short* const sbase = (unsigned short*)smemRaw;
  unsigned short* const sQ = sbase;
  unsigned short* const sK = sbase + 4096;
  unsigned short* const sV = sbase + 8192;
  unsigned short* const sP = sbase + 12288;

  const int tid = threadIdx.x;
  const int l   = tid & 63;
  const int w   = tid >> 6;
  const int bid = blockIdx.x;
  const int b   = bid & 1;
  const int h   = (bid >> 1) & (H_N - 1);
  const int qt  = bid >> 5;
  const int qBase = qt * QB;
  const int bh  = b * H_N + h;

  const int lrow = l & 15;
  const int lq4  = l >> 4;

  const size_t base = (size_t)bh * (size_t)(S_N * D_N);
  const int* const maskRow = mask + b * S_N;

  // ---- stage Q, load A-frags
  {
    StageReg qreg;
    stageLoad(Q + base + (size_t)qBase * D_N, tid, qreg);
    stageWrite(qreg, sQ, tid);
  }
  __syncthreads();

  bf16x8 qf[2];
  {
    const int qrow = w * 16 + lrow;
#pragma unroll
    for (int ks = 0; ks < 2; ++ks) {
      const int cc = ks * 4 + lq4;
      qf[ks] = *(const bf16x8*)&sQ[qrow * 64 + ((cc ^ (qrow & 7)) << 3)];
    }
  }

  // ---- pass 1: row sums of mask * exp(score - 20), async-staged K
  float minv[4];
  {
    float lsum[4] = {0.f, 0.f, 0.f, 0.f};
    StageReg kreg;
    stageLoad(K + base, tid, kreg);
    for (int kt = 0; kt < S_N / KT; ++kt) {
      __syncthreads();
      stageWrite(kreg, sK, tid);
      __syncthreads();
      if (kt + 1 < S_N / KT)
        stageLoad(K + base + (size_t)((kt + 1) * KT) * D_N, tid, kreg);
#pragma unroll
      for (int n = 0; n < 4; ++n) {
        const int krow = n * 16 + lrow;
        f32x4 acc = {0.f, 0.f, 0.f, 0.f};
#pragma unroll
        for (int ks = 0; ks < 2; ++ks) {
          const int cc = ks * 4 + lq4;
          bf16x8 kf = *(const bf16x8*)&sK[krow * 64 + ((cc ^ (krow & 7)) << 3)];
          acc = __builtin_amdgcn_mfma_f32_16x16x32_bf16(qf[ks], kf, acc, 0, 0, 0);
        }
        const float mf = (float)maskRow[kt * KT + krow];
#pragma unroll
        for (int r = 0; r < 4; ++r)
          lsum[r] += mf * exp2f(fmaf(acc[r], EXPC1, EXPC2));
      }
    }
#pragma unroll
    for (int r = 0; r < 4; ++r) {
      float v = lsum[r];
      v += __shfl_xor(v, 1);
      v += __shfl_xor(v, 2);
      v += __shfl_xor(v, 4);
      v += __shfl_xor(v, 8);
      minv[r] = (v > 0.f) ? ((1.0f / 0.9f) / v) : 0.f;
    }
  }

  // ---- pass 2: scores, dropout via bit table, p-store, PV
  f32x4 oacc[4];
#pragma unroll
  for (int n = 0; n < 4; ++n)
    oacc[n] = (f32x4){0.f, 0.f, 0.f, 0.f};

  const uint32_t qg = (uint32_t)(qBase + w * 16 + lq4 * 4);
  const size_t pBase = (size_t)bh * (size_t)(S_N * S_N);
  const uint32_t wq5  = qg >> 5;      // word column (same for r=0..3)
  const uint32_t bsh  = qg & 31u;     // base bit shift

  {
    StageReg kreg, vreg;
    stageLoad(K + base, tid, kreg);
    stageLoad(V + base, tid, vreg);
    for (int kt = 0; kt < S_N / KT; ++kt) {
      __syncthreads();
      stageWrite (kreg, sK, tid);
      stageWriteT(vreg, sV, tid);
      __syncthreads();
      if (kt + 1 < S_N / KT) {
        stageLoad(K + base + (size_t)((kt + 1) * KT) * D_N, tid, kreg);
        stageLoad(V + base + (size_t)((kt + 1) * KT) * D_N, tid, vreg);
      }

#pragma unroll
      for (int n = 0; n < 4; ++n) {
        const int krow = n * 16 + lrow;
        f32x4 acc = {0.f, 0.f, 0.f, 0.f};
#pragma unroll
        for (int ks = 0; ks < 2; ++ks) {
          const int cc = ks * 4 + lq4;
          bf16x8 kf = *(const bf16x8*)&sK[krow * 64 + ((cc ^ (krow & 7)) << 3)];
          acc = __builtin_amdgcn_mfma_f32_16x16x32_bf16(qf[ks], kf, acc, 0, 0, 0);
        }
        const int kg = kt * KT + krow;
        const float mf = (float)maskRow[kg];
        // keep-bit word for this (bh, kg, q-block)
        const uint32_t kb = bits[(((uint32_t)(bh << 11) + (uint32_t)kg) << 6) + wq5] >> bsh;
#pragma unroll
        for (int r = 0; r < 4; ++r) {
          const float pe = mf * exp2f(fmaf(acc[r], EXPC1, EXPC2)) * minv[r];
          const float pd = ((kb >> r) & 1u) ? pe : 0.0f;
          __builtin_nontemporal_store(pd, &outP[pBase + (size_t)(qg + r) * S_N + (size_t)kg]);
          const int prow = w * 16 + lq4 * 4 + r;
          sP[prow * 64 + ((((krow >> 3) ^ (prow & 7)) << 3) | (krow & 7))] = f2bf(pd);
        }
      }
      // PV (sP rows are warp-private)
#pragma unroll
      for (int ks = 0; ks < 2; ++ks) {
        const int cc = ks * 4 + lq4;
        const int prow = w * 16 + lrow;
        bf16x8 af = *(const bf16x8*)&sP[prow * 64 + ((cc ^ (prow & 7)) << 3)];
#pragma unroll
        for (int n = 0; n < 4; ++n) {
          const int vrow = n * 16 + lrow;
          bf16x8 vf = *(const bf16x8*)&sV[vrow * 64 + ((cc ^ (vrow & 7)) << 3)];
          oacc[n] = __builtin_amdgcn_mfma_f32_16x16x32_bf16(af, vf, oacc[n], 0, 0, 0);
        }
      }
    }
  }

  // ---- store out
#pragma unroll
  for (int n = 0; n < 4; ++n)
#pragma unroll
    for (int r = 0; r < 4; ++r) {
      const size_t off = ((size_t)bh * S_N + (size_t)(qg + r)) * D_N + n * 16 + lrow;
      __builtin_nontemporal_store(oacc[n][r], &outO[off]);
    }
}

// ============ Fallback: R8 kernel with inline threefry ============
__global__ __launch_bounds__(256, 4)
void attn_fused_tf(const float* __restrict__ Q, const float* __restrict__ K,
                   const float* __restrict__ V, const int* __restrict__ mask,
                   float* __restrict__ outO, float* __restrict__ outP) {
  __shared__ uint4 smemRaw[2048];
  unsigned short* const sbase = (unsigned short*)smemRaw;
  unsigned short* const sQ = sbase;
  unsigned short* const sK = sbase + 4096;
  unsigned short* const sV = sbase + 8192;
  unsigned short* const sP = sbase + 12288;

  const int tid = threadIdx.x;
  const int l   = tid & 63;
  const int w   = tid >> 6;
  const int bid = blockIdx.x;
  const int b   = bid & 1;
  const int h   = (bid >> 1) & (H_N - 1);
  const int qt  = bid >> 5;
  const int qBase = qt * QB;
  const int bh  = b * H_N + h;

  const int lrow = l & 15;
  const int lq4  = l >> 4;

  const size_t base = (size_t)bh * (size_t)(S_N * D_N);
  const int* const maskRow = mask + b * S_N;

  {
    StageReg qreg;
    stageLoad(Q + base + (size_t)qBase * D_N, tid, qreg);
    stageWrite(qreg, sQ, tid);
  }
  __syncthreads();

  bf16x8 qf[2];
  {
    const int qrow = w * 16 + lrow;
#pragma unroll
    for (int ks = 0; ks < 2; ++ks) {
      const int cc = ks * 4 + lq4;
      qf[ks] = *(const bf16x8*)&sQ[qrow * 64 + ((cc ^ (qrow & 7)) << 3)];
    }
  }

  float minv[4];
  {
    float lsum[4] = {0.f, 0.f, 0.f, 0.f};
    StageReg kreg;
    stageLoad(K + base, tid, kreg);
    for (int kt = 0; kt < S_N / KT; ++kt) {
      __syncthreads();
      stageWrite(kreg, sK, tid);
      __syncthreads();
      if (kt + 1 < S_N / KT)
        stageLoad(K + base + (size_t)((kt + 1) * KT) * D_N, tid, kreg);
#pragma unroll
      for (int n = 0; n < 4; ++n) {
        const int krow = n * 16 + lrow;
        f32x4 acc = {0.f, 0.f, 0.f, 0.f};
#pragma unroll
        for (int ks = 0; ks < 2; ++ks) {
          const int cc = ks * 4 + lq4;
          bf16x8 kf = *(const bf16x8*)&sK[krow * 64 + ((cc ^ (krow & 7)) << 3)];
          acc = __builtin_amdgcn_mfma_f32_16x16x32_bf16(qf[ks], kf, acc, 0, 0, 0);
        }
        const float mf = (float)maskRow[kt * KT + krow];
#pragma unroll
        for (int r = 0; r < 4; ++r)
          lsum[r] += mf * exp2f(fmaf(acc[r], EXPC1, EXPC2));
      }
    }
#pragma unroll
    for (int r = 0; r < 4; ++r) {
      float v = lsum[r];
      v += __shfl_xor(v, 1);
      v += __shfl_xor(v, 2);
      v += __shfl_xor(v, 4);
      v += __shfl_xor(v, 8);
      minv[r] = (v > 0.f) ? ((1.0f / 0.9f) / v) : 0.f;
    }
  }

  f32x4 oacc[4];
#pragma unroll
  for (int n = 0; n < 4; ++n)
    oacc[n] = (f32x4){0.f, 0.f, 0.f, 0.f};

  const uint32_t qg = (uint32_t)(qBase + w * 16 + lq4 * 4);
  const size_t pBase = (size_t)bh * (size_t)(S_N * S_N);
  const uint32_t jBase = (uint32_t)bh * 4194304u + qg * 2048u;

  {
    StageReg kreg, vreg;
    stageLoad(K + base, tid, kreg);
    stageLoad(V + base, tid, vreg);
    for (int kt = 0; kt < S_N / KT; ++kt) {
      __syncthreads();
      stageWrite (kreg, sK, tid);
      stageWriteT(vreg, sV, tid);
      __syncthreads();
      if (kt + 1 < S_N / KT) {
        stageLoad(K + base + (size_t)((kt + 1) * KT) * D_N, tid, kreg);
        stageLoad(V + base + (size_t)((kt + 1) * KT) * D_N, tid, vreg);
      }

#pragma unroll
      for (int n = 0; n < 4; ++n) {
        const int krow = n * 16 + lrow;
        f32x4 acc = {0.f, 0.f, 0.f, 0.f};
#pragma unroll
        for (int ks = 0; ks < 2; ++ks) {
          const int cc = ks * 4 + lq4;
          bf16x8 kf = *(const bf16x8*)&sK[krow * 64 + ((cc ^ (krow & 7)) << 3)];
          acc = __builtin_amdgcn_mfma_f32_16x16x32_bf16(qf[ks], kf, acc, 0, 0, 0);
        }
        const int kg = kt * KT + krow;
        const float mf = (float)maskRow[kg];
        const uint32_t j0 = jBase + (uint32_t)kg;
#pragma unroll
        for (int r = 0; r < 4; ++r) {
          const float pe = mf * exp2f(fmaf(acc[r], EXPC1, EXPC2)) * minv[r];
          const float pd = keep_bit(j0 + (uint32_t)r * 2048u) ? pe : 0.0f;
          __builtin_nontemporal_store(pd, &outP[pBase + (size_t)(qg + r) * S_N + (size_t)kg]);
          const int prow = w * 16 + lq4 * 4 + r;
          sP[prow * 64 + ((((krow >> 3) ^ (prow & 7)) << 3) | (krow & 7))] = f2bf(pd);
        }
      }
#pragma unroll
      for (int ks = 0; ks < 2; ++ks) {
        const int cc = ks * 4 + lq4;
        const int prow = w * 16 + lrow;
        bf16x8 af = *(const bf16x8*)&sP[prow * 64 + ((cc ^ (prow & 7)) << 3)];
#pragma unroll
        for (int n = 0; n < 4; ++n) {
          const int vrow = n * 16 + lrow;
          bf16x8 vf = *(const bf16x8*)&sV[vrow * 64 + ((cc ^ (vrow & 7)) << 3)];
          oacc[n] = __builtin_amdgcn_mfma_f32_16x16x32_bf16(af, vf, oacc[n], 0, 0, 0);
        }
      }
    }
  }

#pragma unroll
  for (int n = 0; n < 4; ++n)
#pragma unroll
    for (int r = 0; r < 4; ++r) {
      const size_t off = ((size_t)bh * S_N + (size_t)(qg + r)) * D_N + n * 16 + lrow;
      __builtin_nontemporal_store(oacc[n][r], &outO[off]);
    }
}

extern "C" void kernel_launch(void* const* d_in, const int* in_sizes, int n_in,
                              void* d_out, int out_size, void* d_ws, size_t ws_size,
                              hipStream_t stream) {
  const float* Q   = (const float*)d_in[0];
  const float* K   = (const float*)d_in[1];
  const float* V   = (const float*)d_in[2];
  const int* mask  = (const int*)d_in[3];
  float* outO = (float*)d_out;
  float* outP = outO + (size_t)2 * H_N * S_N * D_N;   // out first, then p_attn

  const size_t bitsBytes = 4194304ull * 4ull;          // 16.8 MB keep-bit table
  if (d_ws != nullptr && ws_size >= bitsBytes) {
    uint32_t* bits = (uint32_t*)d_ws;
    hipLaunchKernelGGL(rng_bits, dim3(16384), dim3(256), 0, stream, mask, bits);
    hipLaunchKernelGGL(attn_fused_bits, dim3(1024), dim3(256), 0, stream,
                       Q, K, V, mask, bits, outO, outP);
  } else {
    hipLaunchKernelGGL(attn_fused_tf, dim3(1024), dim3(256), 0, stream,
                       Q, K, V, mask, outO, outP);
  }
}